// Round 9
// baseline (655.733 us; speedup 1.0000x reference)
//
#include <hip/hip_runtime.h>

typedef _Float16 f16x8 __attribute__((ext_vector_type(8)));
typedef _Float16 f16x4 __attribute__((ext_vector_type(4)));
typedef float    f32x4 __attribute__((ext_vector_type(4)));

#define BN    64           // points per block
#define KPAD  288          // padded K width for the skip layer
#define ROWB  (KPAD * 2)   // 576 bytes per LDS row
#define WELE  270336       // fp16 elements per weight bank (hi or lo)

// XOR swizzle on the 16B-slot index for cols 0..255 (bytes 0..511).
// Bytes 512..575 (the x/zero pad cols) stay linear so the swizzle never
// escapes the row.
__device__ __forceinline__ int swz(int row, int colb) {
  int c = (colb < 512) ? (colb ^ ((row & 7) << 4)) : colb;
  return row * ROWB + c;
}

__device__ __forceinline__ float gabor_f(float lin) {
  float a = 10.f * lin;                 // OMEGA == SIGMA == 10
  return __cosf(a) * __expf(-a * a);
}

// Next-kk0 weight fragments held across the layer barrier (named members,
// never runtime-indexed -> stays in VGPRs).
struct WPre { f16x8 a0, a1, c0, c1; };

__device__ __forceinline__ void preloadW(WPre& p, const _Float16* __restrict__ Whi,
                                         const _Float16* __restrict__ Wlo,
                                         int ldw, int r, int g, int n0) {
  const int kb = g * 8;
  const size_t o0 = (size_t)(n0 + r) * ldw + kb;
  const size_t o1 = (size_t)(n0 + 16 + r) * ldw + kb;
  p.a0 = *(const f16x8*)(Whi + o0);
  p.a1 = *(const f16x8*)(Whi + o1);
  p.c0 = *(const f16x8*)(Wlo + o0);
  p.c1 = *(const f16x8*)(Wlo + o1);
}

// One 256-out gabor layer, split-precision weights, W-prefetch pipelined one
// kk ahead with sched_barrier(0) fences so the loads issue BEFORE the MFMA
// cluster and the compiler emits counted (non-draining) vmcnt waits.
// In the last kk, next layer's kk0 W is prefetched into `pre` (flies under
// the epilogue + __syncthreads).
template <int KSTEPS>
__device__ __forceinline__ void mfma_layer(const char* __restrict__ inb,
                                           char* __restrict__ outb,
                                           const _Float16* __restrict__ Whi,
                                           const _Float16* __restrict__ Wlo,
                                           const float* __restrict__ bias,
                                           WPre& pre,
                                           const _Float16* __restrict__ nWhi,
                                           const _Float16* __restrict__ nWlo,
                                           int nldw,
                                           int lane, int n0) {
  const int r = lane & 15;
  const int g = lane >> 4;
  f32x4 acc[2][4];
#pragma unroll
  for (int i = 0; i < 2; i++)
#pragma unroll
    for (int j = 0; j < 4; j++) {
      f32x4 z = {0.f, 0.f, 0.f, 0.f};
      acc[i][j] = z;
    }

  // ping-pong W operand sets (kk0 comes in via `pre`)
  f16x8 a[2][2], c[2][2], b[4];
  a[0][0] = pre.a0; a[0][1] = pre.a1;
  c[0][0] = pre.c0; c[0][1] = pre.c1;

#pragma unroll
  for (int kk = 0; kk < KSTEPS; kk++) {
    const int cur = kk & 1;
    const int nxt = cur ^ 1;
    const int kb = kk * 32 + g * 8;

    // B fragments for THIS kk (LDS, low latency, single-buffered)
#pragma unroll
    for (int j = 0; j < 4; j++)
      b[j] = *(const f16x8*)(inb + swz(j * 16 + r, kb * 2));

    if (kk + 1 < KSTEPS) {            // W prefetch for kk+1 (global, L2)
      const int kbn = (kk + 1) * 32 + g * 8;
      const size_t o0 = (size_t)(n0 + r) * (KSTEPS * 32) + kbn;
      const size_t o1 = (size_t)(n0 + 16 + r) * (KSTEPS * 32) + kbn;
      a[nxt][0] = *(const f16x8*)(Whi + o0);
      a[nxt][1] = *(const f16x8*)(Whi + o1);
      c[nxt][0] = *(const f16x8*)(Wlo + o0);
      c[nxt][1] = *(const f16x8*)(Wlo + o1);
    } else if (nWhi) {                // last kk: prefetch NEXT layer's kk0 W
      preloadW(pre, nWhi, nWlo, nldw, r, g, n0);
    }

    // Fence: loads above may not sink below; MFMAs below may not hoist above.
    __builtin_amdgcn_sched_barrier(0);

#pragma unroll
    for (int i = 0; i < 2; i++)
#pragma unroll
      for (int j = 0; j < 4; j++)
        acc[i][j] = __builtin_amdgcn_mfma_f32_16x16x32_f16(a[cur][i], b[j], acc[i][j], 0, 0, 0);
#pragma unroll
    for (int i = 0; i < 2; i++)
#pragma unroll
      for (int j = 0; j < 4; j++)
        acc[i][j] = __builtin_amdgcn_mfma_f32_16x16x32_f16(c[cur][i], b[j], acc[i][j], 0, 0, 0);
  }

  // epilogue: +bias, gabor, pack 4 consecutive units -> one ds_write_b64
#pragma unroll
  for (int i = 0; i < 2; i++) {
    const f32x4 bv = *(const f32x4*)(bias + n0 + i * 16 + g * 4);
#pragma unroll
    for (int j = 0; j < 4; j++) {
      f16x4 hv;
#pragma unroll
      for (int e = 0; e < 4; e++)
        hv[e] = (_Float16)gabor_f(acc[i][j][e] + bv[e]);
      *(f16x4*)(outb + swz(j * 16 + r, (n0 + i * 16 + g * 4) * 2)) = hv;
    }
  }
}

extern "C" __global__ void __launch_bounds__(512, 4)
inr_fused(const float* __restrict__ x, const float* __restrict__ W0,
          const float* __restrict__ b0, const float* __restrict__ b1,
          const float* __restrict__ b2, const float* __restrict__ b3,
          const float* __restrict__ b4, const float* __restrict__ Wf,
          const float* __restrict__ bf, const _Float16* __restrict__ wsh,
          float* __restrict__ out, int npts) {
  extern __shared__ char smem[];
  char* bufA = smem;
  char* bufB = smem + BN * ROWB;

  const _Float16* w1h = wsh;
  const _Float16* w2h = wsh + 65536;
  const _Float16* w4h = wsh + 131072;
  const _Float16* w3p = wsh + 196608;   // [256][288], zero-padded
  const _Float16* w1l = wsh + WELE;
  const _Float16* w2l = wsh + WELE + 65536;
  const _Float16* w4l = wsh + WELE + 131072;
  const _Float16* w3l = wsh + WELE + 196608;

  const int tid   = threadIdx.x;
  const int pbase = blockIdx.x * BN;
  const int lane  = tid & 63;
  const int wid   = tid >> 6;           // 8 waves: 8 unit-slices, all points
  const int n0    = wid * 32;
  const int r     = lane & 15;
  const int g     = lane >> 4;

  // prefetch L1's kk0 weights; they fly during L0 compute + barrier
  WPre pre;
  preloadW(pre, w1h, w1l, 256, r, g, n0);

  // ---- layer 0: K=3 linear + gabor, fp32 VALU; also fill skip cols ----
  {
    const int p = tid >> 3;             // 64 points, 8 threads each
    const int q = tid & 7;              // each thread: 32 units
    const int gp = pbase + p;
    float x0 = 0.f, x1 = 0.f, x2 = 0.f;
    if (gp < npts) {
      x0 = x[(size_t)gp * 3 + 0];
      x1 = x[(size_t)gp * 3 + 1];
      x2 = x[(size_t)gp * 3 + 2];
    }
#pragma unroll
    for (int ub = 0; ub < 32; ub += 8) {
      const int u0 = q * 32 + ub;
      f16x8 hv;
#pragma unroll
      for (int e = 0; e < 8; e++) {
        const int u = u0 + e;
        float lin = fmaf(x0, W0[u * 3 + 0],
                    fmaf(x1, W0[u * 3 + 1],
                    fmaf(x2, W0[u * 3 + 2], b0[u])));
        hv[e] = (_Float16)gabor_f(lin);
      }
      *(f16x8*)(bufA + swz(p, u0 * 2)) = hv;
    }
    // skip-concat cols 256..287 of bufA: [x0,x1,x2, 0...0]
    if (q < 4) {
      f16x8 xv = {(_Float16)0.f, (_Float16)0.f, (_Float16)0.f, (_Float16)0.f,
                  (_Float16)0.f, (_Float16)0.f, (_Float16)0.f, (_Float16)0.f};
      if (q == 0) { xv[0] = (_Float16)x0; xv[1] = (_Float16)x1; xv[2] = (_Float16)x2; }
      *(f16x8*)(bufA + swz(p, (256 + q * 8) * 2)) = xv;
    }
  }
  __syncthreads();

  mfma_layer<8>(bufA, bufB, w1h, w1l, b1, pre, w2h, w2l, 256, lane, n0);  // L1
  __syncthreads();
  mfma_layer<8>(bufB, bufA, w2h, w2l, b2, pre, w3p, w3l, 288, lane, n0);  // L2
  __syncthreads();
  mfma_layer<9>(bufA, bufB, w3p, w3l, b3, pre, w4h, w4l, 256, lane, n0);  // L3 (K=288)
  __syncthreads();
  mfma_layer<8>(bufB, bufA, w4h, w4l, b4, pre, (const _Float16*)nullptr,
                (const _Float16*)nullptr, 0, lane, n0);                   // L4
  __syncthreads();

  // ---- final linear: 3 outputs per point, fp32 VALU ----
  if (tid < BN * 3) {
    const int p = tid / 3;
    const int o = tid - p * 3;
    const int gp = pbase + p;
    if (gp < npts) {
      float a0 = bf[o], a1 = 0.f, a2 = 0.f, a3 = 0.f;
#pragma unroll 4
      for (int k = 0; k < 256; k += 8) {
        f16x8 hv = *(const f16x8*)(bufA + swz(p, k * 2));
        f32x4 wa = *(const f32x4*)(Wf + o * 256 + k);
        f32x4 wb = *(const f32x4*)(Wf + o * 256 + k + 4);
        a0 = fmaf((float)hv[0], wa[0], a0);
        a1 = fmaf((float)hv[1], wa[1], a1);
        a2 = fmaf((float)hv[2], wa[2], a2);
        a3 = fmaf((float)hv[3], wa[3], a3);
        a0 = fmaf((float)hv[4], wb[0], a0);
        a1 = fmaf((float)hv[5], wb[1], a1);
        a2 = fmaf((float)hv[6], wb[2], a2);
        a3 = fmaf((float)hv[7], wb[3], a3);
      }
      out[(size_t)gp * 3 + o] = (a0 + a1) + (a2 + a3);
    }
  }
}

// fp32 -> split fp16 (hi + lo residual) weight conversion into workspace:
// whi bank at [0, WELE), wlo bank at [WELE, 2*WELE). Within each bank:
// [0,65536)    W1 [256][256]
// [65536,..)   W2 [256][256]
// [131072,..)  W4 [256][256]
// [196608,..)  W3 [256][288] zero-padded from [256][259]
extern "C" __global__ void conv_w(const float* __restrict__ W1,
                                  const float* __restrict__ W2,
                                  const float* __restrict__ W4,
                                  const float* __restrict__ W3,
                                  _Float16* __restrict__ wsh) {
  int idx = blockIdx.x * blockDim.x + threadIdx.x;
  float w = 0.f;
  bool valid = false;
  if (idx < 196608) {
    int which = idx >> 16, k = idx & 65535;
    const float* s = (which == 0) ? W1 : ((which == 1) ? W2 : W4);
    w = s[k];
    valid = true;
  } else if (idx < WELE) {
    int t = idx - 196608;
    int j = t / 288, k = t - j * 288;
    w = (k < 259) ? W3[(size_t)j * 259 + k] : 0.f;
    valid = true;
  }
  if (valid) {
    _Float16 hi = (_Float16)w;
    _Float16 lo = (_Float16)(w - (float)hi);
    wsh[idx] = hi;
    wsh[idx + WELE] = lo;
  }
}

extern "C" void kernel_launch(void* const* d_in, const int* in_sizes, int n_in,
                              void* d_out, int out_size, void* d_ws, size_t ws_size,
                              hipStream_t stream) {
  const float* x  = (const float*)d_in[0];
  const float* W0 = (const float*)d_in[1];
  const float* b0 = (const float*)d_in[2];
  const float* W1 = (const float*)d_in[3];
  const float* b1 = (const float*)d_in[4];
  const float* W2 = (const float*)d_in[5];
  const float* b2 = (const float*)d_in[6];
  const float* W3 = (const float*)d_in[7];
  const float* b3 = (const float*)d_in[8];
  const float* W4 = (const float*)d_in[9];
  const float* b4 = (const float*)d_in[10];
  const float* Wf = (const float*)d_in[11];
  const float* bf = (const float*)d_in[12];
  float* out      = (float*)d_out;
  _Float16* wsh   = (_Float16*)d_ws;    // needs 2*WELE*2 B = 1081344 B

  const int npts = in_sizes[0] / 3;

  conv_w<<<(WELE + 511) / 512, 512, 0, stream>>>(W1, W2, W4, W3, wsh);

  const int nblk = (npts + BN - 1) / BN;
  inr_fused<<<nblk, 512, 2 * BN * ROWB, stream>>>(x, W0, b0, b1, b2, b3, b4,
                                                  Wf, bf, wsh, out, npts);
}

// Round 10
// 628.585 us; speedup vs baseline: 1.0432x; 1.0432x over previous
//
#include <hip/hip_runtime.h>
#include <stdint.h>

typedef _Float16 f16x8 __attribute__((ext_vector_type(8)));
typedef _Float16 f16x4 __attribute__((ext_vector_type(4)));
typedef float    f32x4 __attribute__((ext_vector_type(4)));

#define BN    64           // points per block
#define KPAD  288          // padded K width for the skip layer
#define ROWB  (KPAD * 2)   // 576 bytes per LDS row
#define WELE  270336       // fp16 elements per weight bank (hi or lo)
#define LDS_ACT (2 * BN * ROWB)        // 73728 B activation buffers
#define LDS_TOTAL (LDS_ACT + 4096)     // + 4 layer biases (4*256 f32)

// XOR swizzle on the 16B-slot index for cols 0..255 (bytes 0..511).
__device__ __forceinline__ int swz(int row, int colb) {
  int c = (colb < 512) ? (colb ^ ((row & 7) << 4)) : colb;
  return row * ROWB + c;
}

__device__ __forceinline__ float gabor_f(float lin) {
  float a = 10.f * lin;                 // OMEGA == SIGMA == 10
  return __cosf(a) * __expf(-a * a);
}

// One in-flight W fragment set (hi row0, hi row1, lo row0, lo row1).
// Loaded by inline-asm global_load_dwordx4 (invisible to the compiler's
// waitcnt pass); completion enforced ONLY by our manual counted vmcnt.
struct WSet { f32x4 h0, h1, l0, l1; };

#define GLOADX4(dst, p)                                                  \
  asm volatile("global_load_dwordx4 %0, %1, off"                         \
               : "=v"(dst) : "v"((uint64_t)(uintptr_t)(p)))

// Wait until at most N of our W loads remain outstanding; the "+v" ties
// make every consuming MFMA data-dependent on this asm (no hoisting).
#define WAITW4(s) asm volatile("s_waitcnt vmcnt(4)"                      \
  : "+v"((s).h0), "+v"((s).h1), "+v"((s).l0), "+v"((s).l1))
#define WAITW0(s) asm volatile("s_waitcnt vmcnt(0)"                      \
  : "+v"((s).h0), "+v"((s).h1), "+v"((s).l0), "+v"((s).l1))

__device__ __forceinline__ void issueW(WSet& s, const _Float16* Whi,
                                       const _Float16* Wlo, int ldw,
                                       int r, int g, int n0, int kel) {
  const _Float16* p0 = Whi + (size_t)(n0 + r)      * ldw + kel + g * 8;
  const _Float16* p1 = Whi + (size_t)(n0 + 16 + r) * ldw + kel + g * 8;
  const _Float16* q0 = Wlo + (size_t)(n0 + r)      * ldw + kel + g * 8;
  const _Float16* q1 = Wlo + (size_t)(n0 + 16 + r) * ldw + kel + g * 8;
  GLOADX4(s.h0, p0);
  GLOADX4(s.h1, p1);
  GLOADX4(s.l0, q0);
  GLOADX4(s.l1, q1);
}

// One 256-out gabor layer, split-precision weights, asm-pipelined W loads
// (1 kk ahead; last kk issues NEXT layer's kk0 into `pre`, which stays in
// flight across the __syncthreads — the compiler sees no pending vmem, so
// it does not drain vmcnt at the barrier).
template <int KSTEPS>
__device__ __forceinline__ void mfma_layer(const char* __restrict__ inb,
                                           char* __restrict__ outb,
                                           const _Float16* __restrict__ Whi,
                                           const _Float16* __restrict__ Wlo,
                                           const float* __restrict__ lbias,
                                           WSet& pre,
                                           const _Float16* __restrict__ nWhi,
                                           const _Float16* __restrict__ nWlo,
                                           int nldw,
                                           int lane, int n0) {
  const int r = lane & 15;
  const int g = lane >> 4;
  f32x4 acc[2][4];
#pragma unroll
  for (int i = 0; i < 2; i++)
#pragma unroll
    for (int j = 0; j < 4; j++) {
      f32x4 z = {0.f, 0.f, 0.f, 0.f};
      acc[i][j] = z;
    }

  WSet w[2];
  w[0] = pre;                           // kk0 fragments (already in flight)

#pragma unroll
  for (int kk = 0; kk < KSTEPS; kk++) {
    const int cur = kk & 1;
    const int nxt = cur ^ 1;

    if (kk + 1 < KSTEPS) {              // issue kk+1's W loads
      issueW(w[nxt], Whi, Wlo, KSTEPS * 32, r, g, n0, (kk + 1) * 32);
    } else if (nWhi) {                  // last kk: issue next layer's kk0
      issueW(pre, nWhi, nWlo, nldw, r, g, n0, 0);
    }

    // B fragments for THIS kk (LDS; compiler manages lgkmcnt)
    const int kb = kk * 32 + g * 8;
    f16x8 b0 = *(const f16x8*)(inb + swz(0 * 16 + r, kb * 2));
    f16x8 b1 = *(const f16x8*)(inb + swz(1 * 16 + r, kb * 2));
    f16x8 b2 = *(const f16x8*)(inb + swz(2 * 16 + r, kb * 2));
    f16x8 b3 = *(const f16x8*)(inb + swz(3 * 16 + r, kb * 2));

    if (kk + 1 < KSTEPS || nWhi) WAITW4(w[cur]); else WAITW0(w[cur]);

    const f16x8 ah0 = __builtin_bit_cast(f16x8, w[cur].h0);
    const f16x8 ah1 = __builtin_bit_cast(f16x8, w[cur].h1);
    const f16x8 al0 = __builtin_bit_cast(f16x8, w[cur].l0);
    const f16x8 al1 = __builtin_bit_cast(f16x8, w[cur].l1);

    acc[0][0] = __builtin_amdgcn_mfma_f32_16x16x32_f16(ah0, b0, acc[0][0], 0, 0, 0);
    acc[0][1] = __builtin_amdgcn_mfma_f32_16x16x32_f16(ah0, b1, acc[0][1], 0, 0, 0);
    acc[0][2] = __builtin_amdgcn_mfma_f32_16x16x32_f16(ah0, b2, acc[0][2], 0, 0, 0);
    acc[0][3] = __builtin_amdgcn_mfma_f32_16x16x32_f16(ah0, b3, acc[0][3], 0, 0, 0);
    acc[1][0] = __builtin_amdgcn_mfma_f32_16x16x32_f16(ah1, b0, acc[1][0], 0, 0, 0);
    acc[1][1] = __builtin_amdgcn_mfma_f32_16x16x32_f16(ah1, b1, acc[1][1], 0, 0, 0);
    acc[1][2] = __builtin_amdgcn_mfma_f32_16x16x32_f16(ah1, b2, acc[1][2], 0, 0, 0);
    acc[1][3] = __builtin_amdgcn_mfma_f32_16x16x32_f16(ah1, b3, acc[1][3], 0, 0, 0);
    acc[0][0] = __builtin_amdgcn_mfma_f32_16x16x32_f16(al0, b0, acc[0][0], 0, 0, 0);
    acc[0][1] = __builtin_amdgcn_mfma_f32_16x16x32_f16(al0, b1, acc[0][1], 0, 0, 0);
    acc[0][2] = __builtin_amdgcn_mfma_f32_16x16x32_f16(al0, b2, acc[0][2], 0, 0, 0);
    acc[0][3] = __builtin_amdgcn_mfma_f32_16x16x32_f16(al0, b3, acc[0][3], 0, 0, 0);
    acc[1][0] = __builtin_amdgcn_mfma_f32_16x16x32_f16(al1, b0, acc[1][0], 0, 0, 0);
    acc[1][1] = __builtin_amdgcn_mfma_f32_16x16x32_f16(al1, b1, acc[1][1], 0, 0, 0);
    acc[1][2] = __builtin_amdgcn_mfma_f32_16x16x32_f16(al1, b2, acc[1][2], 0, 0, 0);
    acc[1][3] = __builtin_amdgcn_mfma_f32_16x16x32_f16(al1, b3, acc[1][3], 0, 0, 0);
  }

  // epilogue: +bias (from LDS -> no vmem in this region), gabor, pack 4
  // consecutive units -> one ds_write_b64
#pragma unroll
  for (int i = 0; i < 2; i++) {
    const f32x4 bv = *(const f32x4*)(lbias + n0 + i * 16 + g * 4);
#pragma unroll
    for (int j = 0; j < 4; j++) {
      f16x4 hv;
#pragma unroll
      for (int e = 0; e < 4; e++)
        hv[e] = (_Float16)gabor_f(acc[i][j][e] + bv[e]);
      *(f16x4*)(outb + swz(j * 16 + r, (n0 + i * 16 + g * 4) * 2)) = hv;
    }
  }
}

extern "C" __global__ void __launch_bounds__(512, 4)
inr_fused(const float* __restrict__ x, const float* __restrict__ W0,
          const float* __restrict__ b0, const float* __restrict__ b1,
          const float* __restrict__ b2, const float* __restrict__ b3,
          const float* __restrict__ b4, const float* __restrict__ Wf,
          const float* __restrict__ bf, const _Float16* __restrict__ wsh,
          float* __restrict__ out, int npts) {
  extern __shared__ char smem[];
  char* bufA = smem;
  char* bufB = smem + BN * ROWB;
  float* lbias = (float*)(smem + LDS_ACT);   // [4][256]

  const _Float16* w1h = wsh;
  const _Float16* w2h = wsh + 65536;
  const _Float16* w4h = wsh + 131072;
  const _Float16* w3p = wsh + 196608;   // [256][288], zero-padded
  const _Float16* w1l = wsh + WELE;
  const _Float16* w2l = wsh + WELE + 65536;
  const _Float16* w4l = wsh + WELE + 131072;
  const _Float16* w3l = wsh + WELE + 196608;

  const int tid   = threadIdx.x;
  const int pbase = blockIdx.x * BN;
  const int lane  = tid & 63;
  const int wid   = tid >> 6;           // 8 waves: 8 unit-slices, all points
  const int n0    = wid * 32;
  const int r     = lane & 15;
  const int g     = lane >> 4;

  // prime the pipeline: L1's kk0 W fragments fly during L0 compute
  WSet pre;
  issueW(pre, w1h, w1l, 256, r, g, n0, 0);

  // stage the 4 layer biases into LDS (epilogues then have NO global loads)
  if (tid < 256) {
    lbias[tid]       = b1[tid];
    lbias[256 + tid] = b2[tid];
    lbias[512 + tid] = b3[tid];
    lbias[768 + tid] = b4[tid];
  }

  // ---- layer 0: K=3 linear + gabor, fp32 VALU; also fill skip cols ----
  {
    const int p = tid >> 3;             // 64 points, 8 threads each
    const int q = tid & 7;              // each thread: 32 units
    const int gp = pbase + p;
    float x0 = 0.f, x1 = 0.f, x2 = 0.f;
    if (gp < npts) {
      x0 = x[(size_t)gp * 3 + 0];
      x1 = x[(size_t)gp * 3 + 1];
      x2 = x[(size_t)gp * 3 + 2];
    }
#pragma unroll
    for (int ub = 0; ub < 32; ub += 8) {
      const int u0 = q * 32 + ub;
      f16x8 hv;
#pragma unroll
      for (int e = 0; e < 8; e++) {
        const int u = u0 + e;
        float lin = fmaf(x0, W0[u * 3 + 0],
                    fmaf(x1, W0[u * 3 + 1],
                    fmaf(x2, W0[u * 3 + 2], b0[u])));
        hv[e] = (_Float16)gabor_f(lin);
      }
      *(f16x8*)(bufA + swz(p, u0 * 2)) = hv;
    }
    // skip-concat cols 256..287 of bufA: [x0,x1,x2, 0...0]
    if (q < 4) {
      f16x8 xv = {(_Float16)0.f, (_Float16)0.f, (_Float16)0.f, (_Float16)0.f,
                  (_Float16)0.f, (_Float16)0.f, (_Float16)0.f, (_Float16)0.f};
      if (q == 0) { xv[0] = (_Float16)x0; xv[1] = (_Float16)x1; xv[2] = (_Float16)x2; }
      *(f16x8*)(bufA + swz(p, (256 + q * 8) * 2)) = xv;
    }
  }
  __syncthreads();

  mfma_layer<8>(bufA, bufB, w1h, w1l, lbias,       pre, w2h, w2l, 256, lane, n0);
  __syncthreads();
  mfma_layer<8>(bufB, bufA, w2h, w2l, lbias + 256, pre, w3p, w3l, 288, lane, n0);
  __syncthreads();
  mfma_layer<9>(bufA, bufB, w3p, w3l, lbias + 512, pre, w4h, w4l, 256, lane, n0);
  __syncthreads();
  mfma_layer<8>(bufB, bufA, w4h, w4l, lbias + 768, pre, (const _Float16*)nullptr,
                (const _Float16*)nullptr, 0, lane, n0);
  __syncthreads();

  // ---- final linear: 3 outputs per point, fp32 VALU ----
  if (tid < BN * 3) {
    const int p = tid / 3;
    const int o = tid - p * 3;
    const int gp = pbase + p;
    if (gp < npts) {
      float a0 = bf[o], a1 = 0.f, a2 = 0.f, a3 = 0.f;
#pragma unroll 4
      for (int k = 0; k < 256; k += 8) {
        f16x8 hv = *(const f16x8*)(bufA + swz(p, k * 2));
        f32x4 wa = *(const f32x4*)(Wf + o * 256 + k);
        f32x4 wb = *(const f32x4*)(Wf + o * 256 + k + 4);
        a0 = fmaf((float)hv[0], wa[0], a0);
        a1 = fmaf((float)hv[1], wa[1], a1);
        a2 = fmaf((float)hv[2], wa[2], a2);
        a3 = fmaf((float)hv[3], wa[3], a3);
        a0 = fmaf((float)hv[4], wb[0], a0);
        a1 = fmaf((float)hv[5], wb[1], a1);
        a2 = fmaf((float)hv[6], wb[2], a2);
        a3 = fmaf((float)hv[7], wb[3], a3);
      }
      out[(size_t)gp * 3 + o] = (a0 + a1) + (a2 + a3);
    }
  }
}

// fp32 -> split fp16 (hi + lo residual) weight conversion into workspace:
// whi bank at [0, WELE), wlo bank at [WELE, 2*WELE). Within each bank:
// [0,65536)    W1 [256][256]
// [65536,..)   W2 [256][256]
// [131072,..)  W4 [256][256]
// [196608,..)  W3 [256][288] zero-padded from [256][259]
extern "C" __global__ void conv_w(const float* __restrict__ W1,
                                  const float* __restrict__ W2,
                                  const float* __restrict__ W4,
                                  const float* __restrict__ W3,
                                  _Float16* __restrict__ wsh) {
  int idx = blockIdx.x * blockDim.x + threadIdx.x;
  float w = 0.f;
  bool valid = false;
  if (idx < 196608) {
    int which = idx >> 16, k = idx & 65535;
    const float* s = (which == 0) ? W1 : ((which == 1) ? W2 : W4);
    w = s[k];
    valid = true;
  } else if (idx < WELE) {
    int t = idx - 196608;
    int j = t / 288, k = t - j * 288;
    w = (k < 259) ? W3[(size_t)j * 259 + k] : 0.f;
    valid = true;
  }
  if (valid) {
    _Float16 hi = (_Float16)w;
    _Float16 lo = (_Float16)(w - (float)hi);
    wsh[idx] = hi;
    wsh[idx + WELE] = lo;
  }
}

extern "C" void kernel_launch(void* const* d_in, const int* in_sizes, int n_in,
                              void* d_out, int out_size, void* d_ws, size_t ws_size,
                              hipStream_t stream) {
  const float* x  = (const float*)d_in[0];
  const float* W0 = (const float*)d_in[1];
  const float* b0 = (const float*)d_in[2];
  const float* W1 = (const float*)d_in[3];
  const float* b1 = (const float*)d_in[4];
  const float* W2 = (const float*)d_in[5];
  const float* b2 = (const float*)d_in[6];
  const float* W3 = (const float*)d_in[7];
  const float* b3 = (const float*)d_in[8];
  const float* W4 = (const float*)d_in[9];
  const float* b4 = (const float*)d_in[10];
  const float* Wf = (const float*)d_in[11];
  const float* bf = (const float*)d_in[12];
  float* out      = (float*)d_out;
  _Float16* wsh   = (_Float16*)d_ws;    // needs 2*WELE*2 B = 1081344 B

  const int npts = in_sizes[0] / 3;

  conv_w<<<(WELE + 511) / 512, 512, 0, stream>>>(W1, W2, W4, W3, wsh);

  const int nblk = (npts + BN - 1) / BN;
  inr_fused<<<nblk, 512, LDS_TOTAL, stream>>>(x, W0, b0, b1, b2, b3, b4,
                                              Wf, bf, wsh, out, npts);
}

// Round 11
// 401.338 us; speedup vs baseline: 1.6339x; 1.5662x over previous
//
#include <hip/hip_runtime.h>

typedef _Float16 f16x8 __attribute__((ext_vector_type(8)));
typedef _Float16 f16x4 __attribute__((ext_vector_type(4)));
typedef float    f32x4 __attribute__((ext_vector_type(4)));

#define BN    64           // points per block
#define KPAD  288          // padded K width for the skip layer
#define ROWB  (KPAD * 2)   // 576 bytes per LDS row
#define WELE  270336       // fp16 elements per weight bank (hi or lo)

// XOR swizzle on the 16B-slot index for cols 0..255 (bytes 0..511).
__device__ __forceinline__ int swz(int row, int colb) {
  int c = (colb < 512) ? (colb ^ ((row & 7) << 4)) : colb;
  return row * ROWB + c;
}

__device__ __forceinline__ float gabor_f(float lin) {
  float a = 10.f * lin;                 // OMEGA == SIGMA == 10
  return __cosf(a) * __expf(-a * a);
}

// One 256-out gabor layer, split-precision weights in PACKED layout:
// per (slice=wid, kk, i) the 64 lanes' 16B fragments are contiguous, so each
// W load is one sequential 1KB block (8 fully-used 128B lines vs 16 half-used
// at 512B stride before) -> halves the per-CU cache-line request rate, which
// is the measured bottleneck.
// kk order is rotated per block (phase) to de-synchronize the 256 CUs'
// accesses to the shared W stream in L2.
template <int KS>
__device__ __forceinline__ void mfma_layer(const char* __restrict__ inb,
                                           char* __restrict__ outb,
                                           const _Float16* __restrict__ Wh,
                                           const _Float16* __restrict__ Wl,
                                           const float* __restrict__ bias,
                                           int lane, int wid, int phase) {
  const int r = lane & 15;
  const int g = lane >> 4;
  const int n0 = wid * 32;
  f32x4 acc[2][4];
#pragma unroll
  for (int i = 0; i < 2; i++)
#pragma unroll
    for (int j = 0; j < 4; j++) {
      f32x4 z = {0.f, 0.f, 0.f, 0.f};
      acc[i][j] = z;
    }

#pragma unroll
  for (int kk = 0; kk < KS; kk++) {
    int kkr = kk + phase;
    if (kkr >= KS) kkr -= KS;

    // packed W: (( (wid*KS+kkr)*2 + i )*64 + lane)*8 halves
    const int wof = (wid * KS + kkr) * 1024 + lane * 8;
    f16x8 a0 = *(const f16x8*)(Wh + wof);
    f16x8 a1 = *(const f16x8*)(Wh + wof + 512);
    f16x8 c0 = *(const f16x8*)(Wl + wof);
    f16x8 c1 = *(const f16x8*)(Wl + wof + 512);

    const int kb = kkr * 32 + g * 8;    // k element offset for this lane group
    f16x8 b0 = *(const f16x8*)(inb + swz(0 * 16 + r, kb * 2));
    f16x8 b1 = *(const f16x8*)(inb + swz(1 * 16 + r, kb * 2));
    f16x8 b2 = *(const f16x8*)(inb + swz(2 * 16 + r, kb * 2));
    f16x8 b3 = *(const f16x8*)(inb + swz(3 * 16 + r, kb * 2));

    acc[0][0] = __builtin_amdgcn_mfma_f32_16x16x32_f16(a0, b0, acc[0][0], 0, 0, 0);
    acc[0][1] = __builtin_amdgcn_mfma_f32_16x16x32_f16(a0, b1, acc[0][1], 0, 0, 0);
    acc[0][2] = __builtin_amdgcn_mfma_f32_16x16x32_f16(a0, b2, acc[0][2], 0, 0, 0);
    acc[0][3] = __builtin_amdgcn_mfma_f32_16x16x32_f16(a0, b3, acc[0][3], 0, 0, 0);
    acc[1][0] = __builtin_amdgcn_mfma_f32_16x16x32_f16(a1, b0, acc[1][0], 0, 0, 0);
    acc[1][1] = __builtin_amdgcn_mfma_f32_16x16x32_f16(a1, b1, acc[1][1], 0, 0, 0);
    acc[1][2] = __builtin_amdgcn_mfma_f32_16x16x32_f16(a1, b2, acc[1][2], 0, 0, 0);
    acc[1][3] = __builtin_amdgcn_mfma_f32_16x16x32_f16(a1, b3, acc[1][3], 0, 0, 0);
    acc[0][0] = __builtin_amdgcn_mfma_f32_16x16x32_f16(c0, b0, acc[0][0], 0, 0, 0);
    acc[0][1] = __builtin_amdgcn_mfma_f32_16x16x32_f16(c0, b1, acc[0][1], 0, 0, 0);
    acc[0][2] = __builtin_amdgcn_mfma_f32_16x16x32_f16(c0, b2, acc[0][2], 0, 0, 0);
    acc[0][3] = __builtin_amdgcn_mfma_f32_16x16x32_f16(c0, b3, acc[0][3], 0, 0, 0);
    acc[1][0] = __builtin_amdgcn_mfma_f32_16x16x32_f16(c1, b0, acc[1][0], 0, 0, 0);
    acc[1][1] = __builtin_amdgcn_mfma_f32_16x16x32_f16(c1, b1, acc[1][1], 0, 0, 0);
    acc[1][2] = __builtin_amdgcn_mfma_f32_16x16x32_f16(c1, b2, acc[1][2], 0, 0, 0);
    acc[1][3] = __builtin_amdgcn_mfma_f32_16x16x32_f16(c1, b3, acc[1][3], 0, 0, 0);
  }

  // epilogue: +bias, gabor, pack 4 consecutive units -> one ds_write_b64
#pragma unroll
  for (int i = 0; i < 2; i++) {
    const f32x4 bv = *(const f32x4*)(bias + n0 + i * 16 + g * 4);
#pragma unroll
    for (int j = 0; j < 4; j++) {
      f16x4 hv;
#pragma unroll
      for (int e = 0; e < 4; e++)
        hv[e] = (_Float16)gabor_f(acc[i][j][e] + bv[e]);
      *(f16x4*)(outb + swz(j * 16 + r, (n0 + i * 16 + g * 4) * 2)) = hv;
    }
  }
}

extern "C" __global__ void __launch_bounds__(512, 4)
inr_fused(const float* __restrict__ x, const float* __restrict__ W0,
          const float* __restrict__ b0, const float* __restrict__ b1,
          const float* __restrict__ b2, const float* __restrict__ b3,
          const float* __restrict__ b4, const float* __restrict__ Wf,
          const float* __restrict__ bf, const _Float16* __restrict__ wsh,
          float* __restrict__ out, int npts) {
  extern __shared__ char smem[];
  char* bufA = smem;
  char* bufB = smem + BN * ROWB;

  // packed layer bases (halves): L1 @0, L2 @65536, L4 @131072, L3 @196608
  const _Float16* w1h = wsh;
  const _Float16* w2h = wsh + 65536;
  const _Float16* w4h = wsh + 131072;
  const _Float16* w3p = wsh + 196608;
  const _Float16* w1l = wsh + WELE;
  const _Float16* w2l = wsh + WELE + 65536;
  const _Float16* w4l = wsh + WELE + 131072;
  const _Float16* w3l = wsh + WELE + 196608;

  const int tid   = threadIdx.x;
  const int pbase = blockIdx.x * BN;
  const int phase = blockIdx.x & 7;     // kk rotation (de-sync CUs in L2)

  // ---- layer 0: K=3 linear + gabor, fp32 VALU; also fill skip cols ----
  {
    const int p = tid >> 3;             // 64 points, 8 threads each
    const int q = tid & 7;              // each thread: 32 units
    const int gp = pbase + p;
    float x0 = 0.f, x1 = 0.f, x2 = 0.f;
    if (gp < npts) {
      x0 = x[(size_t)gp * 3 + 0];
      x1 = x[(size_t)gp * 3 + 1];
      x2 = x[(size_t)gp * 3 + 2];
    }
#pragma unroll
    for (int ub = 0; ub < 32; ub += 8) {
      const int u0 = q * 32 + ub;
      f16x8 hv;
#pragma unroll
      for (int e = 0; e < 8; e++) {
        const int u = u0 + e;
        float lin = fmaf(x0, W0[u * 3 + 0],
                    fmaf(x1, W0[u * 3 + 1],
                    fmaf(x2, W0[u * 3 + 2], b0[u])));
        hv[e] = (_Float16)gabor_f(lin);
      }
      *(f16x8*)(bufA + swz(p, u0 * 2)) = hv;
    }
    // skip-concat cols 256..287 of bufA: [x0,x1,x2, 0...0]
    if (q < 4) {
      f16x8 xv = {(_Float16)0.f, (_Float16)0.f, (_Float16)0.f, (_Float16)0.f,
                  (_Float16)0.f, (_Float16)0.f, (_Float16)0.f, (_Float16)0.f};
      if (q == 0) { xv[0] = (_Float16)x0; xv[1] = (_Float16)x1; xv[2] = (_Float16)x2; }
      *(f16x8*)(bufA + swz(p, (256 + q * 8) * 2)) = xv;
    }
  }
  __syncthreads();

  const int lane = tid & 63;
  const int wid  = tid >> 6;            // 8 waves: 8 unit-slices, all points

  mfma_layer<8>(bufA, bufB, w1h, w1l, b1, lane, wid, phase);   // L1: A -> B
  __syncthreads();
  mfma_layer<8>(bufB, bufA, w2h, w2l, b2, lane, wid, phase);   // L2: B -> A
  __syncthreads();
  mfma_layer<9>(bufA, bufB, w3p, w3l, b3, lane, wid, phase);   // L3: K=288
  __syncthreads();
  mfma_layer<8>(bufB, bufA, w4h, w4l, b4, lane, wid, phase);   // L4: B -> A
  __syncthreads();

  // ---- final linear: 3 outputs per point, fp32 VALU ----
  if (tid < BN * 3) {
    const int p = tid / 3;
    const int o = tid - p * 3;
    const int gp = pbase + p;
    if (gp < npts) {
      float a0 = bf[o], a1 = 0.f, a2 = 0.f, a3 = 0.f;
#pragma unroll 4
      for (int k = 0; k < 256; k += 8) {
        f16x8 hv = *(const f16x8*)(bufA + swz(p, k * 2));
        f32x4 wa = *(const f32x4*)(Wf + o * 256 + k);
        f32x4 wb = *(const f32x4*)(Wf + o * 256 + k + 4);
        a0 = fmaf((float)hv[0], wa[0], a0);
        a1 = fmaf((float)hv[1], wa[1], a1);
        a2 = fmaf((float)hv[2], wa[2], a2);
        a3 = fmaf((float)hv[3], wa[3], a3);
        a0 = fmaf((float)hv[4], wb[0], a0);
        a1 = fmaf((float)hv[5], wb[1], a1);
        a2 = fmaf((float)hv[6], wb[2], a2);
        a3 = fmaf((float)hv[7], wb[3], a3);
      }
      out[(size_t)gp * 3 + o] = (a0 + a1) + (a2 + a3);
    }
  }
}

// fp32 -> split fp16 (hi + lo residual) weight conversion, PACKED into the
// per-wave MFMA fragment order:
//   packed idx (within layer) = (((slice*KS + kk)*2 + i)*64 + lane)*8 + e
//   source: unit = slice*32 + i*16 + (lane&15); k = kk*32 + (lane>>4)*8 + e
// hi bank at [0, WELE), lo bank at [WELE, 2*WELE). Layer bases (halves):
//   L1 @0 (KS=8), L2 @65536 (KS=8), L4 @131072 (KS=8), L3 @196608 (KS=9,
//   K=288 zero-padded from 259).
extern "C" __global__ void conv_w(const float* __restrict__ W1,
                                  const float* __restrict__ W2,
                                  const float* __restrict__ W4,
                                  const float* __restrict__ W3,
                                  _Float16* __restrict__ wsh) {
  int idx = blockIdx.x * blockDim.x + threadIdx.x;
  if (idx >= WELE) return;

  int base, KS;
  const float* src = nullptr;
  int ldk = 256, kmax = 256;
  if (idx < 65536)       { base = 0;      KS = 8; src = W1; }
  else if (idx < 131072) { base = 65536;  KS = 8; src = W2; }
  else if (idx < 196608) { base = 131072; KS = 8; src = W4; }
  else                   { base = 196608; KS = 9; src = W3; ldk = 259; kmax = 259; }

  const int t    = idx - base;
  const int e    = t & 7;
  const int lane = (t >> 3) & 63;
  const int i    = (t >> 9) & 1;
  const int rem  = t >> 10;
  const int kk   = rem % KS;
  const int slice = rem / KS;

  const int unit = slice * 32 + i * 16 + (lane & 15);
  const int k    = kk * 32 + (lane >> 4) * 8 + e;

  const float w = (k < kmax) ? src[(size_t)unit * ldk + k] : 0.f;
  const _Float16 hi = (_Float16)w;
  const _Float16 lo = (_Float16)(w - (float)hi);
  wsh[idx] = hi;
  wsh[idx + WELE] = lo;
}

extern "C" void kernel_launch(void* const* d_in, const int* in_sizes, int n_in,
                              void* d_out, int out_size, void* d_ws, size_t ws_size,
                              hipStream_t stream) {
  const float* x  = (const float*)d_in[0];
  const float* W0 = (const float*)d_in[1];
  const float* b0 = (const float*)d_in[2];
  const float* W1 = (const float*)d_in[3];
  const float* b1 = (const float*)d_in[4];
  const float* W2 = (const float*)d_in[5];
  const float* b2 = (const float*)d_in[6];
  const float* W3 = (const float*)d_in[7];
  const float* b3 = (const float*)d_in[8];
  const float* W4 = (const float*)d_in[9];
  const float* b4 = (const float*)d_in[10];
  const float* Wf = (const float*)d_in[11];
  const float* bf = (const float*)d_in[12];
  float* out      = (float*)d_out;
  _Float16* wsh   = (_Float16*)d_ws;    // needs 2*WELE*2 B = 1081344 B

  const int npts = in_sizes[0] / 3;

  conv_w<<<(WELE + 511) / 512, 512, 0, stream>>>(W1, W2, W4, W3, wsh);

  const int nblk = (npts + BN - 1) / BN;
  inr_fused<<<nblk, 512, 2 * BN * ROWB, stream>>>(x, W0, b0, b1, b2, b3, b4,
                                                  Wf, bf, wsh, out, npts);
}